// Round 4
// baseline (22.611 us; speedup 1.0000x reference)
//
#include <hip/hip_runtime.h>

constexpr int NE = 8;       // N_ELEMENT
constexpr int NL = 32;      // N_LINES
constexpr int MB = 512;     // MINIBATCH
constexpr int SN = 1024;    // SAMPLE_N
constexpr float KS   = 0.01f / 1024.0f;  // SAMPLE_CM / SAMPLE_N
constexpr float I0   = 100000.0f;        // PROBE_I0
constexpr float OUTS = 0.05f;            // DET_SOLID_ANGLE_RATIO * SIGNAL_ATT

__device__ __forceinline__ unsigned short f2bf(float f) {
    unsigned u = __float_as_uint(f);
    u += 0x7FFFu + ((u >> 16) & 1u);     // round-to-nearest-even
    return (unsigned short)(u >> 16);
}
__device__ __forceinline__ float bf2f(unsigned short h) {
    return __uint_as_float(((unsigned)h) << 16);
}

// ---- K1: prefix scan + weighted-conc (bf16) + transmission ----------------
// One block per batch row. 256 threads; thread t owns samples 4t..4t+3.
__global__ __launch_bounds__(256)
void ppm_scan_kernel(const float* __restrict__ xp,   // [8][512][1024]
                     const float* __restrict__ mu,   // [8]
                     unsigned short* __restrict__ wx,// [8][512][1024] bf16
                     float* __restrict__ out)        // [..| 512 trans]
{
    const int b    = blockIdx.x;
    const int t    = threadIdx.x;
    const int lane = t & 63;
    const int wv   = t >> 6;

    __shared__ float s_wave[4];

    float x[NE][4];
    #pragma unroll
    for (int e = 0; e < NE; ++e) {
        const float4 v = reinterpret_cast<const float4*>(
            xp + (size_t)e * (MB * SN) + (size_t)b * SN)[t];
        x[e][0] = v.x; x[e][1] = v.y; x[e][2] = v.z; x[e][3] = v.w;
    }

    float a0 = 0.f, a1 = 0.f, a2 = 0.f, a3 = 0.f;
    #pragma unroll
    for (int e = 0; e < NE; ++e) {
        const float m = mu[e];
        a0 = fmaf(m, x[e][0], a0);
        a1 = fmaf(m, x[e][1], a1);
        a2 = fmaf(m, x[e][2], a2);
        a3 = fmaf(m, x[e][3], a3);
    }
    const float e1 = a0, e2 = a0 + a1, e3 = e2 + a2;
    const float T  = e3 + a3;

    float incl = T;
    #pragma unroll
    for (int d = 1; d < 64; d <<= 1) {
        const float v = __shfl_up(incl, d, 64);
        if (lane >= d) incl += v;
    }
    if (lane == 63) s_wave[wv] = incl;
    __syncthreads();

    float woff = 0.f;
    #pragma unroll
    for (int w2 = 0; w2 < 4; ++w2) woff += (w2 < wv) ? s_wave[w2] : 0.f;
    const float bex = woff + (incl - T);

    if (t == 0) {
        out[NL * MB + b] = KS * (s_wave[0] + s_wave[1] + s_wave[2] + s_wave[3]);
    }

    const float w0 = I0 * __expf(-KS * bex);
    const float w1 = I0 * __expf(-KS * (bex + e1));
    const float w2 = I0 * __expf(-KS * (bex + e2));
    const float w3 = I0 * __expf(-KS * (bex + e3));

    #pragma unroll
    for (int e = 0; e < NE; ++e) {
        ushort4 o;
        o.x = f2bf(w0 * x[e][0]);
        o.y = f2bf(w1 * x[e][1]);
        o.z = f2bf(w2 * x[e][2]);
        o.w = f2bf(w3 * x[e][3]);
        reinterpret_cast<ushort4*>(wx + (size_t)e * (MB * SN) + (size_t)b * SN)[t] = o;
    }
}

// ---- K2: 16384 independent (line, batch) dot-products ---------------------
// 4096 blocks x 256 threads; one wave per (l,b) pair. Pure streaming.
__global__ __launch_bounds__(256)
void ppm_dot_kernel(const unsigned short* __restrict__ wx, // [8][512][1024] bf16
                    const float* __restrict__ fl,          // [32]
                    const float* __restrict__ SA,          // [32][512*1024]
                    float* __restrict__ out)               // [32*512 | ...]
{
    const int lane = threadIdx.x & 63;
    const int wv   = threadIdx.x >> 6;          // 0..3
    const int p    = blockIdx.x * 4 + wv;       // 0..16383
    const int l    = p >> 9;                    // 0..31
    const int b    = p & 511;                   // 0..511
    const int e    = l >> 2;

    const float4*  sa4 = reinterpret_cast<const float4*>(
        SA + (size_t)l * (size_t)(MB * SN) + (size_t)b * SN);
    const ushort4* wx4 = reinterpret_cast<const ushort4*>(
        wx + (size_t)e * (size_t)(MB * SN) + (size_t)b * SN);

    float acc = 0.f;
    #pragma unroll
    for (int j = 0; j < 4; ++j) {
        const int idx = lane + 64 * j;
        const float4  sa = sa4[idx];
        const ushort4 wq = wx4[idx];
        acc += bf2f(wq.x) * sa.x + bf2f(wq.y) * sa.y
             + bf2f(wq.z) * sa.z + bf2f(wq.w) * sa.w;
    }
    #pragma unroll
    for (int d = 32; d >= 1; d >>= 1) acc += __shfl_down(acc, d, 64);
    if (lane == 0) out[l * MB + b] = OUTS * fl[l] * acc;
}

extern "C" void kernel_launch(void* const* d_in, const int* in_sizes, int n_in,
                              void* d_out, int out_size, void* d_ws, size_t ws_size,
                              hipStream_t stream) {
    const float* xp = (const float*)d_in[0];
    const float* mu = (const float*)d_in[1];
    const float* fl = (const float*)d_in[2];
    const float* SA = (const float*)d_in[3];
    float* out = (float*)d_out;
    unsigned short* wx = (unsigned short*)d_ws;   // 8 MB bf16 scratch

    ppm_scan_kernel<<<MB, 256, 0, stream>>>(xp, mu, wx, out);
    ppm_dot_kernel<<<NL * MB / 4, 256, 0, stream>>>(wx, fl, SA, out);
}

// Round 5
// 22.090 us; speedup vs baseline: 1.0236x; 1.0236x over previous
//
#include <hip/hip_runtime.h>

constexpr int NE = 8;       // N_ELEMENT
constexpr int NL = 32;      // N_LINES
constexpr int MB = 512;     // MINIBATCH
constexpr int SN = 1024;    // SAMPLE_N
constexpr float KS   = 0.01f / 1024.0f;  // SAMPLE_CM / SAMPLE_N
constexpr float I0   = 100000.0f;        // PROBE_I0
constexpr float OUTS = 0.05f;            // DET_SOLID_ANGLE_RATIO * SIGNAL_ATT

// One block per batch row b. 1024 threads (16 waves), 1 sample per thread.
// Load order is the whole trick: xp loads are issued FIRST (oldest in the
// vmcnt queue), SA prefetch SECOND. The scan then waits only vmcnt(8) --
// the 8 SA loads stay in flight across the scan + barriers, so the 64 MB
// SA stream overlaps the serial scan phase instead of serializing after it.
__global__ __launch_bounds__(1024)
void ppm_kernel(const float* __restrict__ xp,   // [8][512][1024]
                const float* __restrict__ mu,   // [8]
                const float* __restrict__ fl,   // [32]
                const float* __restrict__ SA,   // [32][512*1024]
                float* __restrict__ out)        // [32*512 fl_signal | 512 trans]
{
    const int b    = blockIdx.x;
    const int t    = threadIdx.x;
    const int lane = t & 63;
    const int wv   = t >> 6;                    // 0..15

    __shared__ float s_wave[16];
    __shared__ float s_wx[NE][SN];              // weighted conc, 32 KB

    // ---- 1) xp loads FIRST: sample t for all 8 elements (coalesced) ----
    float x[NE];
    #pragma unroll
    for (int e = 0; e < NE; ++e) {
        x[e] = xp[(size_t)e * (MB * SN) + (size_t)b * SN + t];
    }

    // ---- 2) SA prefetch SECOND (consumed last, stays in flight) ----
    // wave wv owns lines wv and wv+16; lane covers samples lane+64j.
    float4 sa[2][4];
    #pragma unroll
    for (int li = 0; li < 2; ++li) {
        const int l = wv + 16 * li;
        const float4* sa4 = reinterpret_cast<const float4*>(
            SA + (size_t)l * (size_t)(MB * SN) + (size_t)b * SN);
        #pragma unroll
        for (int j = 0; j < 4; ++j) sa[li][j] = sa4[lane + 64 * j];
    }

    // ---- 3) attenuation increment (waits only on xp: vmcnt(8)) ----
    float a = 0.f;
    #pragma unroll
    for (int e = 0; e < NE; ++e) a = fmaf(mu[e], x[e], a);

    // ---- wave-level inclusive scan (width 64) ----
    float incl = a;
    #pragma unroll
    for (int d = 1; d < 64; d <<= 1) {
        const float v = __shfl_up(incl, d, 64);
        if (lane >= d) incl += v;
    }
    if (lane == 63) s_wave[wv] = incl;
    __syncthreads();

    // cross-wave exclusive offset
    float woff = 0.f;
    #pragma unroll
    for (int w2 = 0; w2 < 16; ++w2) woff += (w2 < wv) ? s_wave[w2] : 0.f;
    const float pex = woff + (incl - a);        // block-level exclusive prefix
    const float w   = I0 * __expf(-KS * pex);   // attenuation weight for sample t

    // transmission_att_exponent[b] = KS * grand total
    if (t == 0) {
        float tot = 0.f;
        #pragma unroll
        for (int w2 = 0; w2 < 16; ++w2) tot += s_wave[w2];
        out[NL * MB + b] = KS * tot;
    }

    // ---- stage weighted conc in LDS ----
    #pragma unroll
    for (int e = 0; e < NE; ++e) s_wx[e][t] = w * x[e];
    __syncthreads();

    // ---- each wave reduces its 2 lines (SA already in registers) ----
    #pragma unroll
    for (int li = 0; li < 2; ++li) {
        const int l = wv + 16 * li;
        const int e = l >> 2;
        const float4* wx4 = reinterpret_cast<const float4*>(&s_wx[e][0]);
        float acc = 0.f;
        #pragma unroll
        for (int j = 0; j < 4; ++j) {
            const float4 wx = wx4[lane + 64 * j];
            acc += wx.x * sa[li][j].x + wx.y * sa[li][j].y
                 + wx.z * sa[li][j].z + wx.w * sa[li][j].w;
        }
        // wave shuffle reduction
        #pragma unroll
        for (int d = 32; d >= 1; d >>= 1) acc += __shfl_down(acc, d, 64);
        if (lane == 0) out[l * MB + b] = OUTS * fl[l] * acc;
    }
}

extern "C" void kernel_launch(void* const* d_in, const int* in_sizes, int n_in,
                              void* d_out, int out_size, void* d_ws, size_t ws_size,
                              hipStream_t stream) {
    const float* xp = (const float*)d_in[0];
    const float* mu = (const float*)d_in[1];
    const float* fl = (const float*)d_in[2];
    const float* SA = (const float*)d_in[3];
    float* out = (float*)d_out;
    ppm_kernel<<<MB, 1024, 0, stream>>>(xp, mu, fl, SA, out);
}